// Round 4
// baseline (259.286 us; speedup 1.0000x reference)
//
#include <hip/hip_runtime.h>
#include <math.h>

// Problem constants: B=128, FEW=64, D=512, E=16, O=512, H=64, K=3
constexpr int Dd  = 512;
constexpr int En  = 16;
constexpr int On  = 512;
constexpr int Hn  = 64;

// Workspace layout (bytes):
//   topi : int  [8192*4]   @ 0        -- top-3 expert ids (slot 3 unused)
//   topv : float[8192*4]   @ 131072   -- top-3 gate probs
//   A    : float[128*16*64]@ 262144   -- gate-weighted hidden accum
//   gsum : float[128*16]   @ 786432   -- gate mass per (batch, expert)

// ---------------------------------------------------------------------------
// K1: gating. 512 blocks x 256 threads; block = 16 tokens.
// x[16][512] staged in LDS via linear coalesced loads; compute reads x as
// LDS broadcast (uniform address, conflict-free) and gW1 per-lane coalesced
// VMEM (address contains lane -> never scalarized). No readfirstlane/asm.
// ---------------------------------------------------------------------------
__global__ __launch_bounds__(256) void k_gate(
    const float* __restrict__ x, const float* __restrict__ gW1,
    const float* __restrict__ gb1, const float* __restrict__ gW2,
    const float* __restrict__ gb2, int* __restrict__ topi,
    float* __restrict__ topv)
{
    __shared__ float xlds[16 * 512];  // 32 KB token tile
    __shared__ float g1l[16 * 65];    // relu hidden (padded)
    __shared__ float logl[16 * 17];   // logits (padded)
    __shared__ float w2l[64 * 16];
    __shared__ float b2l[16];

    const int tid = threadIdx.x;
    const int ln  = tid & 63;
    const int wv  = tid >> 6;
    const int t0  = blockIdx.x * 16;

    // stage gW2 / gb2
    #pragma unroll
    for (int k = 0; k < 4; k++) w2l[tid + k * 256] = gW2[tid + k * 256];
    if (tid < 16) b2l[tid] = gb2[tid];

    // stage x tile: 2048 float4, linear (consecutive lanes -> consecutive 16B
    // in both global and LDS: coalesced reads, conflict-free writes)
    #pragma unroll
    for (int k = 0; k < 8; k++) {
        const int f   = tid + k * 256;   // float4 index in tile
        const int tok = f >> 7;          // 128 float4 per row
        const int df4 = f & 127;
        ((float4*)xlds)[f] =
            *(const float4*)(x + (size_t)(t0 + tok) * Dd + df4 * 4);
    }
    __syncthreads();

    // hidden: wave wv handles tokens wv*4..wv*4+3, lane = h
    float acc[4];
    const float gb1v = gb1[ln];
    #pragma unroll
    for (int i = 0; i < 4; i++) acc[i] = gb1v;

    float w[4];
    #pragma unroll
    for (int j = 0; j < 4; j++) w[j] = gW1[j * 64 + ln];

    for (int dq = 0; dq < 512; dq += 4) {
        const int dn = (dq + 4) & 511;   // branch-free tail prefetch
        float wn[4];
        #pragma unroll
        for (int j = 0; j < 4; j++) wn[j] = gW1[(dn + j) * 64 + ln];
        #pragma unroll
        for (int i = 0; i < 4; i++) {
            const float4 xv = *(const float4*)&xlds[(wv * 4 + i) * 512 + dq];
            acc[i] = fmaf(xv.x, w[0], acc[i]);
            acc[i] = fmaf(xv.y, w[1], acc[i]);
            acc[i] = fmaf(xv.z, w[2], acc[i]);
            acc[i] = fmaf(xv.w, w[3], acc[i]);
        }
        #pragma unroll
        for (int j = 0; j < 4; j++) w[j] = wn[j];
    }

    #pragma unroll
    for (int i = 0; i < 4; i++) g1l[(wv * 4 + i) * 65 + ln] = fmaxf(acc[i], 0.f);
    __syncthreads();

    // logits: 16 tokens x 16 experts = 256 -> one per thread
    {
        const int tok = tid >> 4;
        const int e   = tid & 15;
        float s = b2l[e];
        const float* g = &g1l[tok * 65];
        #pragma unroll 8
        for (int h = 0; h < 64; h++) s = fmaf(g[h], w2l[h * 16 + e], s);
        logl[tok * 17 + e] = s;
    }
    __syncthreads();

    // softmax + top-3 (strict > keeps lowest index on ties, matching lax.top_k)
    if (tid < 16) {
        float v[16];
        float mx = -1e30f;
        #pragma unroll
        for (int e = 0; e < 16; e++) { v[e] = logl[tid * 17 + e]; mx = fmaxf(mx, v[e]); }
        float ssum = 0.f;
        #pragma unroll
        for (int e = 0; e < 16; e++) { v[e] = __expf(v[e] - mx); ssum += v[e]; }
        const float inv = 1.f / ssum;
        #pragma unroll
        for (int e = 0; e < 16; e++) v[e] *= inv;
        const int t = t0 + tid;
        unsigned mask = 0;
        for (int j = 0; j < 3; j++) {
            float bv = -1.f; int bi = 0;
            for (int e = 0; e < 16; e++) {
                if (!(mask & (1u << e)) && v[e] > bv) { bv = v[e]; bi = e; }
            }
            mask |= (1u << bi);
            topi[t * 4 + j] = bi;
            topv[t * 4 + j] = bv;
        }
    }
}

// ---------------------------------------------------------------------------
// K2: sparse expert fc1 + gate-weighted accumulation.
// Grid 1024 = 16 experts x 64 slices of 128 tokens. Block (e,s) owns
// A[2s..2s+1, e, :] -> plain stores. Per 32-token batch: loop 4 d-chunks,
// staging W1[e] chunk [128d][64h] (32 KB) + gathered x tile [32tok][128d]
// (16 KB) in LDS with linear coalesced loads; compute reads W per-lane b32
// (2-way, free) and x as broadcast b128. All barriers block-uniform.
// ---------------------------------------------------------------------------
__global__ __launch_bounds__(256) void k_expert(
    const float* __restrict__ x, const float* __restrict__ W1,
    const float* __restrict__ b1, const int* __restrict__ topi,
    const float* __restrict__ topv, float* __restrict__ A,
    float* __restrict__ gsum)
{
    __shared__ float wlds[128 * 64];   // 32 KB W chunk [d][h]
    __shared__ float xlds[32 * 128];   // 16 KB x tile  [tok][d]
    __shared__ int   lt[128];
    __shared__ float lv[128];
    __shared__ float Ap[2 * 64];
    __shared__ float gp[2];
    __shared__ int   cnt;

    const int tid = threadIdx.x;
    const int ln  = tid & 63;
    const int wv  = tid >> 6;
    const int e   = blockIdx.x >> 6;    // expert 0..15
    const int s   = blockIdx.x & 63;    // slice 0..63
    const int ts  = s * 128;

    if (tid == 0) cnt = 0;
    if (tid < 128) Ap[tid] = 0.f;
    if (tid < 2) gp[tid] = 0.f;
    __syncthreads();

    // compact tokens of this slice that picked expert e
    if (tid < 128) {
        const int t = ts + tid;
        const int4   ti = *(const int4*)(topi + t * 4);
        const float4 tv = *(const float4*)(topv + t * 4);
        const int   idx[3] = { ti.x, ti.y, ti.z };
        const float val[3] = { tv.x, tv.y, tv.z };
        #pragma unroll
        for (int j = 0; j < 3; j++) {
            if (idx[j] == e) {
                const int p = atomicAdd(&cnt, 1);
                lt[p] = tid;
                lv[p] = val[j];
                atomicAdd(&gp[tid >> 6], val[j]);
            }
        }
    }
    __syncthreads();
    const int n = cnt;   // block-uniform

    const float b1v = b1[e * 64 + ln];
    const float* __restrict__ W1e = W1 + (size_t)e * (Dd * Hn);

    for (int bs = 0; bs < n; bs += 32) {      // uniform trip count
        // wave slot metadata (lt/lv stable after compaction barrier)
        int   tt[8]; float mv[8]; int bl[8];
        #pragma unroll
        for (int i = 0; i < 8; i++) {
            const int slot = bs + wv * 8 + i;
            tt[i] = (slot < n) ? lt[slot] : 0;
            mv[i] = (slot < n) ? lv[slot] : 0.f;
            bl[i] = tt[i] >> 6;
        }
        float acc[8];
        #pragma unroll
        for (int i = 0; i < 8; i++) acc[i] = 0.f;

        for (int c = 0; c < 4; c++) {
            __syncthreads();   // protect LDS tiles from previous compute
            // stage W chunk: 2048 float4 linear, coalesced
            #pragma unroll
            for (int k = 0; k < 8; k++)
                ((float4*)wlds)[tid + k * 256] =
                    ((const float4*)(W1e + c * 8192))[tid + k * 256];
            // stage x tile: 1024 float4 linear; gather rows via lt
            #pragma unroll
            for (int k = 0; k < 4; k++) {
                const int f    = tid + k * 256;
                const int tokl = f >> 5;          // 32 float4 per row
                const int df4  = f & 31;
                const int tg   = (bs + tokl < n) ? lt[bs + tokl] : 0;
                ((float4*)xlds)[f] =
                    *(const float4*)(x + (size_t)(ts + tg) * Dd + c * 128 + df4 * 4);
            }
            __syncthreads();

            for (int dq = 0; dq < 128; dq += 4) {
                const float w0 = wlds[(dq + 0) * 64 + ln];
                const float w1 = wlds[(dq + 1) * 64 + ln];
                const float w2 = wlds[(dq + 2) * 64 + ln];
                const float w3 = wlds[(dq + 3) * 64 + ln];
                #pragma unroll
                for (int i = 0; i < 8; i++) {
                    const float4 xv = *(const float4*)&xlds[(wv * 8 + i) * 128 + dq];
                    acc[i] = fmaf(xv.x, w0, acc[i]);
                    acc[i] = fmaf(xv.y, w1, acc[i]);
                    acc[i] = fmaf(xv.z, w2, acc[i]);
                    acc[i] = fmaf(xv.w, w3, acc[i]);
                }
            }
        }

        #pragma unroll
        for (int i = 0; i < 8; i++) {
            const float h = fmaxf(acc[i] + b1v, 0.f);
            atomicAdd(&Ap[bl[i] * 64 + ln], mv[i] * h);
        }
    }
    __syncthreads();

    // sole owner of (2s..2s+1, e) -> plain stores (also covers ws poison)
    if (tid < 128) {
        const int bl2 = tid >> 6, h = tid & 63;
        A[(size_t)(s * 2 + bl2) * (En * Hn) + e * 64 + h] = Ap[tid];
    }
    if (tid < 2) gsum[(s * 2 + tid) * En + e] = gp[tid];
}

// ---------------------------------------------------------------------------
// K3: out[b, o] = (A[b] . W2 + gsum[b] . b2) / 64
// Grid 256 = 32 batch-quads x 8 column-octs. Wave = one batch; lane = one
// output column -> W2 row reads are 256 B coalesced. A staged in LDS.
// ---------------------------------------------------------------------------
__global__ __launch_bounds__(256) void k_out(
    const float* __restrict__ W2, const float* __restrict__ b2,
    const float* __restrict__ A, const float* __restrict__ gsum,
    float* __restrict__ out)
{
    __shared__ float Al[4096];   // A for 4 batches
    __shared__ float gl[64];

    const int tid = threadIdx.x;
    const int ln  = tid & 63;
    const int wv  = tid >> 6;              // wave = which of 4 batches
    const int bq  = blockIdx.x >> 3;       // 0..31
    const int oc  = blockIdx.x & 7;        // 0..7
    const int b0  = bq * 4;
    const int o   = oc * 64 + ln;

    #pragma unroll
    for (int k = 0; k < 4; k++)
        ((float4*)Al)[tid + k * 256] = ((const float4*)(A + (size_t)b0 * 1024))[tid + k * 256];
    if (tid < 64) gl[tid] = gsum[b0 * En + tid];
    __syncthreads();

    const int ab = wv * 1024;
    const float* w2p = W2 + o;
    float a = 0.f;

    float wc[8];
    #pragma unroll
    for (int j = 0; j < 8; j++) wc[j] = w2p[(size_t)j * On];

    for (int eh = 0; eh < 1024; eh += 8) {
        const int en = (eh + 8) & 1023;
        float wn[8];
        #pragma unroll
        for (int j = 0; j < 8; j++) wn[j] = w2p[(size_t)(en + j) * On];
        const float4 a0 = *(const float4*)&Al[ab + eh];
        const float4 a1 = *(const float4*)&Al[ab + eh + 4];
        a = fmaf(a0.x, wc[0], a);
        a = fmaf(a0.y, wc[1], a);
        a = fmaf(a0.z, wc[2], a);
        a = fmaf(a0.w, wc[3], a);
        a = fmaf(a1.x, wc[4], a);
        a = fmaf(a1.y, wc[5], a);
        a = fmaf(a1.z, wc[6], a);
        a = fmaf(a1.w, wc[7], a);
        #pragma unroll
        for (int j = 0; j < 8; j++) wc[j] = wn[j];
    }
    #pragma unroll
    for (int ee = 0; ee < 16; ee++) a = fmaf(gl[wv * 16 + ee], b2[ee * On + o], a);

    out[(size_t)(b0 + wv) * On + o] = a * (1.f / 64.f);
}

// ---------------------------------------------------------------------------
extern "C" void kernel_launch(void* const* d_in, const int* in_sizes, int n_in,
                              void* d_out, int out_size, void* d_ws, size_t ws_size,
                              hipStream_t stream)
{
    (void)in_sizes; (void)n_in; (void)out_size; (void)ws_size;
    const float* x   = (const float*)d_in[0];
    const float* gW1 = (const float*)d_in[1];
    const float* gb1 = (const float*)d_in[2];
    const float* gW2 = (const float*)d_in[3];
    const float* gb2 = (const float*)d_in[4];
    const float* W1  = (const float*)d_in[5];
    const float* b1  = (const float*)d_in[6];
    const float* W2  = (const float*)d_in[7];
    const float* b2  = (const float*)d_in[8];
    float* out = (float*)d_out;

    char* ws = (char*)d_ws;
    int*   topi = (int*)(ws);
    float* topv = (float*)(ws + 131072);
    float* A    = (float*)(ws + 262144);
    float* gsum = (float*)(ws + 786432);

    k_gate  <<<dim3(512),  dim3(256), 0, stream>>>(x, gW1, gb1, gW2, gb2, topi, topv);
    k_expert<<<dim3(1024), dim3(256), 0, stream>>>(x, W1, b1, topi, topv, A, gsum);
    k_out   <<<dim3(256),  dim3(256), 0, stream>>>(W2, b2, A, gsum, out);
}